// Round 3
// baseline (596.485 us; speedup 1.0000x reference)
//
#include <hip/hip_runtime.h>

// LittleBitITQSpecLinear: y = sum_b ((x*v2_b) @ sign(V_b)^T * (v1_b*u2_b)) @ sign(U_b)^T * u1_b + bias
// Folded: W1_b[s,k] = sign(V_b[s,k])*v2_b[k];  W2_b[o,s] = sign(U_b[o,s])*v1_b[s]*u2_b[s]*u1_b[o]
// => H = Xbf16 @ W1cat^T  (8192x2048, K=4096);  Y = H @ W2cat^T + bias (8192x4096, K=2048)
//
// R2: fetch-side XOR-swizzled LDS -> SQ_LDS_BANK_CONFLICT 5e7 -> 0, GEMM 167->139us (988 TF).
// R3: ping-pong LDS double-buffer, ONE barrier per K-iter. Loads for chunk i+1
//     issued before compute of chunk i -> the vmcnt(0) drain at the barrier waits
//     on loads that already had ~300 cyc in flight. Targets the ~29% barrier-drain
//     stall. LDS 32->64 KB (2 blocks/CU). Also fused cast_x+prep_w into one launch.

typedef __bf16 bf16x8 __attribute__((ext_vector_type(8)));
typedef float floatx4 __attribute__((ext_vector_type(4)));

__device__ __forceinline__ unsigned short f2bf_rne(float f) {
    union { float f; unsigned u; } v; v.f = f;
    unsigned r = v.u + 0x7FFFu + ((v.u >> 16) & 1u);
    return (unsigned short)(r >> 16);
}

__device__ __forceinline__ float sgnf(float w) {
    return (float)((w > 0.f) - (w < 0.f));
}

__device__ __forceinline__ void async_copy16(const void* g, void* l) {
    __builtin_amdgcn_global_load_lds(
        (const __attribute__((address_space(1))) void*)g,
        (__attribute__((address_space(3))) void*)l, 16, 0, 0);
}

// ---------------- fused prep kernel ----------------
// Blocks [0,32768): cast x (fp32 -> bf16), 4 elems/thread.
// Blocks [32768,40960): W1cat[s_cat][k] (2048x4096).
// Blocks [40960,49152): W2cat[o][s_cat] (4096x2048).
__global__ void prep_all_kernel(const float* __restrict__ x, unsigned short* __restrict__ Xb,
                                const float* __restrict__ V, const float* __restrict__ V_R,
                                const float* __restrict__ v2, const float* __restrict__ v2_R,
                                const float* __restrict__ U, const float* __restrict__ U_R,
                                const float* __restrict__ v1, const float* __restrict__ v1_R,
                                const float* __restrict__ u2, const float* __restrict__ u2_R,
                                const float* __restrict__ u1, const float* __restrict__ u1_R,
                                unsigned short* __restrict__ W1,
                                unsigned short* __restrict__ W2) {
    int bid = blockIdx.x;
    if (bid < 32768) {
        int i = bid * blockDim.x + threadIdx.x;
        float4 v = ((const float4*)x)[i];
        ushort4 o;
        o.x = f2bf_rne(v.x); o.y = f2bf_rne(v.y);
        o.z = f2bf_rne(v.z); o.w = f2bf_rne(v.w);
        ((ushort4*)Xb)[i] = o;
    } else if (bid < 40960) {
        int i = (bid - 32768) * blockDim.x + threadIdx.x;
        int idx = i << 2;
        int scat = idx >> 12;
        int k = idx & 4095;
        const float* Vp; const float* sp;
        if (scat < 1024) { Vp = V + ((size_t)scat << 12); sp = v2; }
        else             { Vp = V_R + ((size_t)(scat - 1024) << 12); sp = v2_R; }
        float4 w = *(const float4*)(Vp + k);
        float4 s = *(const float4*)(sp + k);
        ushort4 o;
        o.x = f2bf_rne(sgnf(w.x) * s.x);
        o.y = f2bf_rne(sgnf(w.y) * s.y);
        o.z = f2bf_rne(sgnf(w.z) * s.z);
        o.w = f2bf_rne(sgnf(w.w) * s.w);
        ((ushort4*)W1)[i] = o;
    } else {
        int i = (bid - 40960) * blockDim.x + threadIdx.x;
        int idx = i << 2;
        int o = idx >> 11;
        int scat = idx & 2047;
        int branch = scat >> 10;
        int s = scat & 1023;
        const float* Up  = branch ? U_R  : U;
        const float* v1p = branch ? v1_R : v1;
        const float* u2p = branch ? u2_R : u2;
        float u1v = (branch ? u1_R : u1)[o];
        float4 w = *(const float4*)(Up + ((size_t)o << 10) + s);
        float4 a = *(const float4*)(v1p + s);
        float4 b = *(const float4*)(u2p + s);
        ushort4 out;
        out.x = f2bf_rne(sgnf(w.x) * a.x * b.x * u1v);
        out.y = f2bf_rne(sgnf(w.y) * a.y * b.y * u1v);
        out.z = f2bf_rne(sgnf(w.z) * a.z * b.z * u1v);
        out.w = f2bf_rne(sgnf(w.w) * a.w * b.w * u1v);
        ((ushort4*)W2)[i] = out;
    }
}

// ---------------- GEMM: C[M,N] = A[M,K] @ B[N,K]^T ----------------
// 128x128 block tile, 4 waves (each 64x64 via 4x4 MFMA 16x16x32), BK=64,
// global_load_lds width-16, XOR-swizzled chunks, ping-pong LDS dbuf.

template <bool OUT_BF16, bool ADD_BIAS>
__global__ __launch_bounds__(256)
void gemm_bt(const unsigned short* __restrict__ A,
             const unsigned short* __restrict__ B,
             void* __restrict__ Cv,
             const float* __restrict__ bias,
             int M, int N, int K) {
    __shared__ __align__(16) unsigned short As[2][128 * 64];
    __shared__ __align__(16) unsigned short Bs[2][128 * 64];

    const int tid = threadIdx.x;
    const int wave = tid >> 6;
    const int lane = tid & 63;
    const int m0 = blockIdx.x * 128;
    const int n0 = blockIdx.y * 128;

    // staging: per wave-instruction, 64 lanes x 16B = 8 rows of 64 bf16.
    // Fetch-side XOR swizzle: LDS[r][c] = global[r][c ^ (r&7)].
    const int lrow = lane >> 3;                         // 0..7
    const int lcol = (((lane & 7) ^ lrow)) << 3;        // swizzled chunk * 8 elems

    // fragment indexing
    const int wm = (wave >> 1) << 6;     // 0 or 64
    const int wn = (wave & 1) << 6;      // 0 or 64
    const int fm = lane & 15;
    const int rk = lane & 7;             // read xor key = (row & 7)
    const int cgl = lane >> 4;           // chunk bits 0-1 from lane

    floatx4 acc[4][4];
#pragma unroll
    for (int i = 0; i < 4; ++i)
#pragma unroll
        for (int j = 0; j < 4; ++j)
#pragma unroll
            for (int r = 0; r < 4; ++r) acc[i][j][r] = 0.f;

    const size_t Ks = (size_t)K;
    const int srow = wave * 32;          // wave-uniform staging base row

    // prologue: stage chunk 0 into buffer 0
#pragma unroll
    for (int i = 0; i < 4; ++i) {
        const int row = srow + i * 8;
        async_copy16(A + (size_t)(m0 + row + lrow) * Ks + lcol, &As[0][row * 64]);
        async_copy16(B + (size_t)(n0 + row + lrow) * Ks + lcol, &Bs[0][row * 64]);
    }
    __syncthreads();

    int p = 0;
    for (int k0 = 0; k0 < K; k0 += 64) {
        // prefetch chunk k0+64 into buffer 1-p (overlaps with compute below)
        if (k0 + 64 < K) {
            const int kn = k0 + 64;
#pragma unroll
            for (int i = 0; i < 4; ++i) {
                const int row = srow + i * 8;
                async_copy16(A + (size_t)(m0 + row + lrow) * Ks + (kn + lcol), &As[1 - p][row * 64]);
                async_copy16(B + (size_t)(n0 + row + lrow) * Ks + (kn + lcol), &Bs[1 - p][row * 64]);
            }
        }
        // compute chunk k0 from buffer p
#pragma unroll
        for (int ks = 0; ks < 64; ks += 32) {
            const int cg = (ks >> 3) | cgl;              // global chunk 0..7
            const int roff = (cg ^ rk) << 3;             // swizzled elem offset
            bf16x8 af[4], bfr[4];
#pragma unroll
            for (int i = 0; i < 4; ++i)
                af[i] = *(const bf16x8*)&As[p][(wm + i * 16 + fm) * 64 + roff];
#pragma unroll
            for (int i = 0; i < 4; ++i)
                bfr[i] = *(const bf16x8*)&Bs[p][(wn + i * 16 + fm) * 64 + roff];
#pragma unroll
            for (int mi = 0; mi < 4; ++mi)
#pragma unroll
                for (int ni = 0; ni < 4; ++ni)
                    acc[mi][ni] = __builtin_amdgcn_mfma_f32_16x16x32_bf16(
                        af[mi], bfr[ni], acc[mi][ni], 0, 0, 0);
        }
        // one barrier per iter: drains prefetch (in flight during compute) and
        // fences reads of buffer p before iter k0+128 overwrites it.
        __syncthreads();
        p ^= 1;
    }

    // epilogue: C/D layout col=lane&15, row=(lane>>4)*4+reg  [m89-verified]
    const int rq = (lane >> 4) << 2;
    const int col = lane & 15;
#pragma unroll
    for (int mi = 0; mi < 4; ++mi) {
#pragma unroll
        for (int r = 0; r < 4; ++r) {
            const int gm = m0 + wm + mi * 16 + rq + r;
            const size_t base = (size_t)gm * (size_t)N;
#pragma unroll
            for (int ni = 0; ni < 4; ++ni) {
                const int gn = n0 + wn + ni * 16 + col;
                float v = acc[mi][ni][r];
                if (ADD_BIAS) v += bias[gn];
                if (OUT_BF16)
                    ((unsigned short*)Cv)[base + gn] = f2bf_rne(v);
                else
                    ((float*)Cv)[base + gn] = v;
            }
        }
    }
}

// ---------------- launch ----------------

extern "C" void kernel_launch(void* const* d_in, const int* in_sizes, int n_in,
                              void* d_out, int out_size, void* d_ws, size_t ws_size,
                              hipStream_t stream) {
    const float* x    = (const float*)d_in[0];
    const float* V    = (const float*)d_in[1];
    const float* U    = (const float*)d_in[2];
    const float* v2   = (const float*)d_in[3];
    const float* v1   = (const float*)d_in[4];
    const float* u2   = (const float*)d_in[5];
    const float* u1   = (const float*)d_in[6];
    const float* V_R  = (const float*)d_in[7];
    const float* U_R  = (const float*)d_in[8];
    const float* v2_R = (const float*)d_in[9];
    const float* v1_R = (const float*)d_in[10];
    const float* u2_R = (const float*)d_in[11];
    const float* u1_R = (const float*)d_in[12];
    const float* bias = (const float*)d_in[13];
    float* out = (float*)d_out;

    char* ws = (char*)d_ws;
    unsigned short* Xb = (unsigned short*)ws;                                   // 8192*4096*2 = 64 MiB
    unsigned short* W1 = (unsigned short*)(ws + (size_t)67108864);              // 2048*4096*2 = 16 MiB
    unsigned short* W2 = (unsigned short*)(ws + (size_t)67108864 + 16777216);   // 4096*2048*2 = 16 MiB
    unsigned short* H  = (unsigned short*)(ws + (size_t)67108864 + 33554432);   // 8192*2048*2 = 32 MiB

    // fused prep: 32768 (cast x) + 8192 (W1) + 8192 (W2) blocks
    prep_all_kernel<<<49152, 256, 0, stream>>>(x, Xb, V, V_R, v2, v2_R,
                                               U, U_R, v1, v1_R, u2, u2_R, u1, u1_R,
                                               W1, W2);

    // GEMM1: H[8192,2048] = Xb @ W1^T, K=4096
    gemm_bt<true, false><<<dim3(64, 16), 256, 0, stream>>>(Xb, W1, (void*)H, nullptr, 8192, 2048, 4096);
    // GEMM2: Y[8192,4096] = H @ W2^T + bias, K=2048
    gemm_bt<false, true><<<dim3(64, 32), 256, 0, stream>>>(H, W2, (void*)out, bias, 8192, 4096, 2048);
}